// Round 8
// baseline (188.933 us; speedup 1.0000x reference)
//
#include <hip/hip_runtime.h>
#include <hip/hip_bf16.h>
#include <math.h>
#include <stdint.h>

#define B 8
#define S 4096
#define D 256
#define H 256
#define FEAT 1794
#define R (B*S)
#define DH (D*H)
#define NCH 64   // s-chunks; chunk size = S/NCH = 64

typedef __bf16 bf16_t;
typedef __bf16 bf16x8 __attribute__((ext_vector_type(8)));
typedef float f32x4 __attribute__((ext_vector_type(4)));

#define GLOAD16(gp, lp) __builtin_amdgcn_global_load_lds( \
  (const __attribute__((address_space(1))) void*)(gp), \
  (__attribute__((address_space(3))) void*)(lp), 16, 0, 0)

__device__ __forceinline__ float waveReduceSum(float v) {
  #pragma unroll
  for (int off = 32; off; off >>= 1) v += __shfl_xor(v, off, 64);
  return v;
}

// ---------- once-per-launch ----------

// Fused: blocks [0, R*D/2048) convert c->CBF, |c-q|->AQB;
// blocks [R*D/2048, +DH/256) build WAQ/WAM from w1.
__global__ void k_prec(const float* __restrict__ c, const float* __restrict__ q,
                       const float* __restrict__ w1,
                       bf16_t* __restrict__ CBF, bf16_t* __restrict__ AQB,
                       bf16_t* __restrict__ WAQ, bf16_t* __restrict__ WAM) {
  const int PREC_BLKS = R*D/2048;
  if (blockIdx.x < PREC_BLKS) {
    int gid = blockIdx.x * 256 + threadIdx.x;   // R*D/8
    int r = gid >> 5;
    int k0 = (gid & 31) * 8;
    int b = r >> 12;
    const float* cp = c + (size_t)r*D + k0;
    const float* qp = q + b*D + k0;
    float cv[8], qv[8];
    *(float4*)(cv)   = *(const float4*)(cp);
    *(float4*)(cv+4) = *(const float4*)(cp + 4);
    *(float4*)(qv)   = *(const float4*)(qp);
    *(float4*)(qv+4) = *(const float4*)(qp + 4);
    bf16x8 cb, ab;
    #pragma unroll
    for (int i = 0; i < 8; i++) {
      cb[i] = (bf16_t)cv[i];
      ab[i] = (bf16_t)fabsf(cv[i] - qv[i]);
    }
    *(bf16x8*)(CBF + (size_t)gid*8) = cb;
    *(bf16x8*)(AQB + (size_t)gid*8) = ab;
  } else {
    int idx = (blockIdx.x - PREC_BLKS) * 256 + threadIdx.x;   // DH
    int h = idx >> 8, k = idx & 255;
    const float* w1h = w1 + (size_t)h * FEAT;
    WAQ[idx] = (bf16_t)w1h[5*D + k];
    WAM[idx] = (bf16_t)w1h[6*D + k];
  }
}

// vq[b][t] = A[t,:].q[b,:]  (one wave per output); also m0 := q.
__global__ void k_p02(const float* __restrict__ q, const float* __restrict__ A,
                      float* __restrict__ vq, float* __restrict__ m0) {
  const int blk = blockIdx.x;              // B*64
  const int b = blk >> 6;
  const int lane = threadIdx.x & 63, wave = threadIdx.x >> 6;
  const int t = (blk & 63)*4 + wave;
  const int l4 = lane * 4;
  float4 q4 = *(const float4*)(q + b*D + l4);
  float4 a4 = *(const float4*)(A + (size_t)t*D + l4);
  float s = a4.x*q4.x + a4.y*q4.y + a4.z*q4.z + a4.w*q4.w;
  s = waveReduceSum(s);
  if (lane == 0) vq[b*D + t] = s;
  if (threadIdx.x < 4) {
    const int tt = (blk & 63)*4 + threadIdx.x;
    m0[b*D + tt] = q[b*D + tt];
  }
}

// ---------- per-hop ----------

// Fused pm2+comb. Grid: B*8 blocks x 1024 thr. Block (b,p):
//  - vm (all 256) into LDS (recomputed per block, never global)
//  - hb[b][p*32 .. p*32+32) to global
//  - WCB[b][h][k] for h in [p*32, p*32+32)
__global__ __launch_bounds__(1024) void k_prep(
    const float* __restrict__ A, const float* __restrict__ w1,
    const float* __restrict__ b1, const float* __restrict__ q,
    const float* __restrict__ min_, const float* __restrict__ vq,
    float* __restrict__ hb, bf16_t* __restrict__ WCB) {
  const int blk = blockIdx.x;
  const int b = blk >> 3, p = blk & 7;
  const int t = threadIdx.x;
  const int lane = t & 63, wave = t >> 6;   // 16 waves
  __shared__ float qsh[D], msh[D], vqsh[D], vmsh[D];
  if (t < 256) {
    qsh[t]  = q[b*D + t];
    msh[t]  = min_[b*D + t];
    vqsh[t] = vq[b*D + t];
  }
  __syncthreads();
  const int l4 = lane * 4;
  const float4 m4 = *(const float4*)(msh + l4);
  const float4 q4 = *(const float4*)(qsh + l4);
  // vm: 256 outputs, 16 per wave
  #pragma unroll
  for (int rep = 0; rep < 16; rep++) {
    const int k = wave*16 + rep;
    const float4 a4 = *(const float4*)(A + (size_t)k*D + l4);
    float s = a4.x*m4.x + a4.y*m4.y + a4.z*m4.z + a4.w*m4.w;
    s = waveReduceSum(s);
    if (lane == 0) vmsh[k] = s;
  }
  // hb: 32 outputs for this p-slice, 2 per wave
  #pragma unroll
  for (int j = 0; j < 2; j++) {
    const int th = p*32 + wave*2 + j;
    const float* w1r = w1 + (size_t)th*FEAT;
    float2 wm0 = *(const float2*)(w1r + D + l4);
    float2 wm1 = *(const float2*)(w1r + D + l4 + 2);
    float2 wq0 = *(const float2*)(w1r + 2*D + l4);
    float2 wq1 = *(const float2*)(w1r + 2*D + l4 + 2);
    float sh = m4.x*wm0.x + m4.y*wm0.y + m4.z*wm1.x + m4.w*wm1.y
             + q4.x*wq0.x + q4.y*wq0.y + q4.z*wq1.x + q4.w*wq1.y;
    sh = waveReduceSum(sh);
    if (lane == 0) hb[b*H + th] = b1[th] + sh;
  }
  __syncthreads();
  // WCB slice: 32 h x 256 k = 8192 elems / 1024 thr = 8 iters
  #pragma unroll
  for (int it = 0; it < 8; it++) {
    const int idx = it*1024 + t;
    const int hl = idx >> 8, k = idx & 255;
    const int h = p*32 + hl;
    const float* w1h = w1 + (size_t)h*FEAT;
    float v = w1h[k] + qsh[k]*w1h[3*D + k] + msh[k]*w1h[4*D + k]
            + vqsh[k]*w1h[7*D] + vmsh[k]*w1h[7*D + 1];
    WCB[(size_t)b*DH + h*256 + k] = (bf16_t)v;
  }
}

// MFMA score v4 (unchanged from round 7): 2-stream LDS-staged A (c, |c-q|),
// |c-m| computed in-kernel. 64 rows x 256 cols, 8 waves.
__global__ __launch_bounds__(512, 4) void k_score4(
    const bf16_t* __restrict__ CBF, const bf16_t* __restrict__ AQB,
    const bf16_t* __restrict__ WCB, const bf16_t* __restrict__ WAQ,
    const bf16_t* __restrict__ WAM, const float* __restrict__ min_,
    const float* __restrict__ hb, const float* __restrict__ w2,
    const float* __restrict__ b2, float* __restrict__ scores) {
  __shared__ char smem[32768];
  __shared__ bf16_t msh[256];
  __shared__ float red[8][64];
  const int t = threadIdx.x;
  const int lane = t & 63, wave = t >> 6;
  const int r0 = blockIdx.x * 64;
  const int b = r0 >> 12;
  const int lrow = lane & 15;
  const int lk = (lane >> 4) * 8;
  const int n0 = wave * 32;

  if (t < 256) msh[t] = (bf16_t)min_[b*D + t];

  const char* cC = (const char*)CBF;
  const char* cQ = (const char*)AQB;
  const bf16_t* bptrC = WCB + (size_t)b*DH;
  const bf16_t* bptrQ = WAQ;
  const bf16_t* bptrM = WAM;

  const int g_off = ((lane >> 3) << 9) + ((((lane & 7) ^ (lane >> 3))) << 4);
  const size_t rowbytes0 = (size_t)r0 << 9;
  const int wave2 = wave * 2;

  f32x4 acc[4][2];
  #pragma unroll
  for (int mi = 0; mi < 4; mi++)
    #pragma unroll
    for (int ni = 0; ni < 2; ni++) acc[mi][ni] = (f32x4){0.f,0.f,0.f,0.f};

  bf16x8 breg[2][6];
  #define LOADB(ks) { \
    const int kelem = (ks)*32 + lk; \
    _Pragma("unroll") \
    for (int ni = 0; ni < 2; ni++) { \
      const size_t co = (size_t)(n0 + ni*16 + lrow) * D + kelem; \
      breg[(ks)&1][ni*3+0] = *(const bf16x8*)(bptrC + co); \
      breg[(ks)&1][ni*3+1] = *(const bf16x8*)(bptrQ + co); \
      breg[(ks)&1][ni*3+2] = *(const bf16x8*)(bptrM + co); \
    } }

  #define STAGE(ch, d) { \
    const int kbyte = (ch) << 7; \
    _Pragma("unroll") \
    for (int j = 0; j < 2; j++) { \
      const int idx = wave2 + j; \
      const int s_ = idx >> 3; \
      const int r8 = (idx & 7) << 3; \
      const char* gsrc = (s_ ? cQ : cC) \
                       + rowbytes0 + ((size_t)r8 << 9) + kbyte + g_off; \
      GLOAD16(gsrc, smem + (d)*16384 + idx*1024); \
    } }

  LOADB(0);
  STAGE(0, 0);
  __syncthreads();

  #pragma unroll
  for (int ch = 0; ch < 4; ch++) {
    if (ch < 3) STAGE(ch + 1, (ch + 1) & 1);
    #pragma unroll
    for (int kk = 0; kk < 2; kk++) {
      const int ks = ch*2 + kk;
      if (ks < 7) LOADB(ks + 1);
      bf16x8 msl = *(const bf16x8*)(msh + ks*32 + lk);
      float mslf[8];
      #pragma unroll
      for (int i = 0; i < 8; i++) mslf[i] = (float)msl[i];
      const int p = ((kk << 2) + (lane >> 4)) ^ (lane & 7);
      const char* lb = smem + (ch & 1)*16384;
      #pragma unroll
      for (int mi = 0; mi < 4; mi++) {
        const int ro = (mi*16 + lrow)*128 + p*16;
        bf16x8 ac = *(const bf16x8*)(lb + ro);
        bf16x8 aq = *(const bf16x8*)(lb + 8192 + ro);
        bf16x8 am;
        #pragma unroll
        for (int i = 0; i < 8; i++) am[i] = (bf16_t)fabsf((float)ac[i] - mslf[i]);
        #pragma unroll
        for (int ni = 0; ni < 2; ni++) {
          acc[mi][ni] = __builtin_amdgcn_mfma_f32_16x16x32_bf16(ac, breg[ks&1][ni*3+0], acc[mi][ni], 0, 0, 0);
          acc[mi][ni] = __builtin_amdgcn_mfma_f32_16x16x32_bf16(aq, breg[ks&1][ni*3+1], acc[mi][ni], 0, 0, 0);
          acc[mi][ni] = __builtin_amdgcn_mfma_f32_16x16x32_bf16(am, breg[ks&1][ni*3+2], acc[mi][ni], 0, 0, 0);
        }
      }
    }
    __syncthreads();
  }

  float hbv[2], w2v[2];
  #pragma unroll
  for (int ni = 0; ni < 2; ni++) {
    const int col = n0 + ni*16 + lrow;
    hbv[ni] = hb[b*H + col];
    w2v[ni] = w2[col];
  }
  #pragma unroll
  for (int mi = 0; mi < 4; mi++) {
    #pragma unroll
    for (int j = 0; j < 4; j++) {
      float ps = 0.f;
      #pragma unroll
      for (int ni = 0; ni < 2; ni++) {
        float x = acc[mi][ni][j] + hbv[ni];
        float ex = __expf(2.f * x);
        float th = 1.f - 2.f * __builtin_amdgcn_rcpf(ex + 1.f);
        ps += th * w2v[ni];
      }
      ps += __shfl_xor(ps, 1, 64);
      ps += __shfl_xor(ps, 2, 64);
      ps += __shfl_xor(ps, 4, 64);
      ps += __shfl_xor(ps, 8, 64);
      if (lrow == 0) red[wave][mi*16 + (lane >> 4)*4 + j] = ps;
    }
  }
  __syncthreads();
  if (t < 64) {
    float s = red[0][t] + red[1][t] + red[2][t] + red[3][t]
            + red[4][t] + red[5][t] + red[6][t] + red[7][t] + b2[0];
    scores[r0 + t] = s;
  }
}

// Fused softmax + att-write + e-partial. Grid B*NCH x 256 thr.
// Each block redundantly reduces its batch's max/sum from sc (L2-hit),
// writes att for its 64-s chunk, accumulates epart.
__global__ __launch_bounds__(256) void k_epart2(
    const bf16_t* __restrict__ CBF, const float* __restrict__ scores,
    const int* __restrict__ len_c, float* __restrict__ att,
    float* __restrict__ epart) {
  const int b = blockIdx.x >> 6, ch = blockIdx.x & 63;
  const int t = threadIdx.x;
  const int len = len_c[b];
  __shared__ float rbuf[4];
  __shared__ float esh[64];
  const float* scb = scores + b*S;

  // per-batch max
  float v[16];
  *(float4*)(v)    = *(const float4*)(scb + t*16);
  *(float4*)(v+4)  = *(const float4*)(scb + t*16 + 4);
  *(float4*)(v+8)  = *(const float4*)(scb + t*16 + 8);
  *(float4*)(v+12) = *(const float4*)(scb + t*16 + 12);
  float mx = -1e30f;
  #pragma unroll
  for (int i = 0; i < 16; i++) if (t*16 + i < len) mx = fmaxf(mx, v[i]);
  #pragma unroll
  for (int off = 32; off; off >>= 1) mx = fmaxf(mx, __shfl_xor(mx, off, 64));
  if ((t & 63) == 0) rbuf[t >> 6] = mx;
  __syncthreads();
  mx = fmaxf(fmaxf(rbuf[0], rbuf[1]), fmaxf(rbuf[2], rbuf[3]));
  __syncthreads();
  // per-batch sum
  float sum = 0.f;
  #pragma unroll
  for (int i = 0; i < 16; i++) if (t*16 + i < len) sum += __expf(v[i] - mx);
  sum = waveReduceSum(sum);
  if ((t & 63) == 0) rbuf[t >> 6] = sum;
  __syncthreads();
  const float inv = 1.f / (rbuf[0] + rbuf[1] + rbuf[2] + rbuf[3]);

  // att for this chunk + esh
  const int s0 = ch * 64;
  if (t < 64) {
    const int s = s0 + t;
    float e = (s < len) ? __expf(scb[s] - mx) * inv : 0.f;
    att[b*S + s] = e;
    esh[t] = e;
  }
  __syncthreads();

  const int cnt = min(64, max(0, len - s0));
  float acc = 0.f;
  int j = 0;
  for (; j + 3 < cnt; j += 4) {
    const bf16_t* cp = CBF + (size_t)(b*S + s0 + j)*D + t;
    acc += esh[j]*(float)cp[0] + esh[j+1]*(float)cp[D]
         + esh[j+2]*(float)cp[2*D] + esh[j+3]*(float)cp[3*D];
  }
  for (; j < cnt; j++) acc += esh[j] * (float)CBF[(size_t)(b*S + s0 + j)*D + t];
  epart[(ch*B + b)*D + t] = acc;
}

// GRU (unchanged): es = sum(epart); 6 coalesced wave-dots per t; gates.
__global__ __launch_bounds__(256) void k_gru2(
    const float* __restrict__ wih, const float* __restrict__ whh,
    const float* __restrict__ bih, const float* __restrict__ bhh,
    const float* __restrict__ epart, const float* __restrict__ min_,
    float* __restrict__ mout, float* __restrict__ out, const int write_out) {
  const int blk = blockIdx.x;         // B*16
  const int b = blk >> 4;
  const int t0 = (blk & 15) << 4;
  const int t = threadIdx.x;
  const int lane = t & 63, wave = t >> 6;
  __shared__ float es[D], ms[D];
  float e = 0.f;
  #pragma unroll
  for (int ch = 0; ch < NCH; ch++) e += epart[(ch*B + b)*D + t];
  es[t] = e;
  ms[t] = min_[b*D + t];
  __syncthreads();
  const int l4 = lane * 4;
  float4 e4 = *(const float4*)(es + l4);
  float4 m4 = *(const float4*)(ms + l4);
  #pragma unroll
  for (int tl = 0; tl < 4; tl++) {
    const int tt = t0 + wave*4 + tl;
    float g[6];
    #pragma unroll
    for (int gg = 0; gg < 3; gg++) {
      const int j = gg*D + tt;
      const float4 wi4 = *(const float4*)(wih + (size_t)j*D + l4);
      const float4 wh4 = *(const float4*)(whh + (size_t)j*D + l4);
      float gi = e4.x*wi4.x + e4.y*wi4.y + e4.z*wi4.z + e4.w*wi4.w;
      float gh = m4.x*wh4.x + m4.y*wh4.y + m4.z*wh4.z + m4.w*wh4.w;
      g[gg]   = waveReduceSum(gi);
      g[3+gg] = waveReduceSum(gh);
    }
    if (lane == 0) {
      const int j0 = tt, j1 = D + tt, j2 = 2*D + tt;
      float gir = g[0] + bih[j0], giz = g[1] + bih[j1], gin = g[2] + bih[j2];
      float ghr = g[3] + bhh[j0], ghz = g[4] + bhh[j1], ghn = g[5] + bhh[j2];
      float rr = 1.f / (1.f + __expf(-(gir + ghr)));
      float zz = 1.f / (1.f + __expf(-(giz + ghz)));
      float nn = tanhf(gin + rr * ghn);
      float mn = (1.f - zz)*nn + zz*ms[tt];
      mout[b*D + tt] = mn;
      if (write_out) out[b*D + tt] = mn;
    }
  }
}

extern "C" void kernel_launch(void* const* d_in, const int* in_sizes, int n_in,
                              void* d_out, int out_size, void* d_ws, size_t ws_size,
                              hipStream_t stream) {
  const float* c   = (const float*)d_in[0];
  const float* q   = (const float*)d_in[1];
  const int*   len = (const int*)d_in[2];
  const float* A   = (const float*)d_in[3];
  const float* w1  = (const float*)d_in[4];
  const float* b1  = (const float*)d_in[5];
  const float* w2  = (const float*)d_in[6];
  const float* b2  = (const float*)d_in[7];
  const float* wih = (const float*)d_in[8];
  const float* whh = (const float*)d_in[9];
  const float* bih = (const float*)d_in[10];
  const float* bhh = (const float*)d_in[11];
  float* out = (float*)d_out;

  bf16_t* WCB = (bf16_t*)d_ws;
  bf16_t* WAQ = WCB + (size_t)B*DH;
  bf16_t* WAM = WAQ + DH;
  bf16_t* CBF = WAM + DH;
  bf16_t* AQB = CBF + (size_t)R*D;
  float* fb = (float*)(AQB + (size_t)R*D);
  float* vq    = fb;
  float* hb    = vq + B*D;
  float* m0    = hb + B*H;
  float* m1    = m0 + B*D;
  float* epart = m1 + B*D;
  float* sc    = epart + (size_t)NCH*B*D;

  k_prec<<<R*D/2048 + DH/256, 256, 0, stream>>>(c, q, w1, CBF, AQB, WAQ, WAM);
  k_p02<<<B*64, 256, 0, stream>>>(q, A, vq, m0);

  for (int it = 0; it < 3; ++it) {
    float* min_ = (it & 1) ? m1 : m0;
    float* mout = (it & 1) ? m0 : m1;
    k_prep<<<B*8, 1024, 0, stream>>>(A, w1, b1, q, min_, vq, hb, WCB);
    k_score4<<<R/64, 512, 0, stream>>>(CBF, AQB, WCB, WAQ, WAM, min_, hb, w2, b2, sc);
    float* att = out + B*D + (size_t)it*R;
    k_epart2<<<B*NCH, 256, 0, stream>>>(CBF, sc, len, att, epart);
    k_gru2<<<B*16, 256, 0, stream>>>(wih, whh, bih, bhh, epart, min_, mout, out, it == 2 ? 1 : 0);
  }
}

// Round 9
// 161.967 us; speedup vs baseline: 1.1665x; 1.1665x over previous
//
#include <hip/hip_runtime.h>
#include <hip/hip_bf16.h>
#include <math.h>
#include <stdint.h>

#define B 8
#define S 4096
#define D 256
#define H 256
#define FEAT 1794
#define R (B*S)
#define DH (D*H)
#define NCH 64   // s-chunks for e partial reduction

typedef __bf16 bf16_t;
typedef __bf16 bf16x8 __attribute__((ext_vector_type(8)));
typedef float f32x4 __attribute__((ext_vector_type(4)));

__device__ __forceinline__ float waveReduceSum(float v) {
  #pragma unroll
  for (int off = 32; off; off >>= 1) v += __shfl_xor(v, off, 64);
  return v;
}

// ---------- once-per-launch ----------

// blocks [0, R*D/2048): CBF = bf16(c); tail blocks: WAQ/WAM from w1.
__global__ void k_prec(const float* __restrict__ c, const float* __restrict__ w1,
                       bf16_t* __restrict__ CBF,
                       bf16_t* __restrict__ WAQ, bf16_t* __restrict__ WAM) {
  const int PREC_BLKS = R*D/2048;
  if (blockIdx.x < PREC_BLKS) {
    int gid = blockIdx.x * 256 + threadIdx.x;   // R*D/8
    const float* cp = c + (size_t)gid*8;
    float cv[8];
    *(float4*)(cv)   = *(const float4*)(cp);
    *(float4*)(cv+4) = *(const float4*)(cp + 4);
    bf16x8 cb;
    #pragma unroll
    for (int i = 0; i < 8; i++) cb[i] = (bf16_t)cv[i];
    *(bf16x8*)(CBF + (size_t)gid*8) = cb;
  } else {
    int idx = (blockIdx.x - PREC_BLKS) * 256 + threadIdx.x;   // DH
    int h = idx >> 8, k = idx & 255;
    const float* w1h = w1 + (size_t)h * FEAT;
    WAQ[idx] = (bf16_t)w1h[5*D + k];
    WAM[idx] = (bf16_t)w1h[6*D + k];
  }
}

// vq[b][t] = A[t,:].q[b,:]  (one wave per output); also m0 := q.
__global__ void k_p02(const float* __restrict__ q, const float* __restrict__ A,
                      float* __restrict__ vq, float* __restrict__ m0) {
  const int blk = blockIdx.x;              // B*64
  const int b = blk >> 6;
  const int lane = threadIdx.x & 63, wave = threadIdx.x >> 6;
  const int t = (blk & 63)*4 + wave;
  const int l4 = lane * 4;
  float4 q4 = *(const float4*)(q + b*D + l4);
  float4 a4 = *(const float4*)(A + (size_t)t*D + l4);
  float s = a4.x*q4.x + a4.y*q4.y + a4.z*q4.z + a4.w*q4.w;
  s = waveReduceSum(s);
  if (lane == 0) vq[b*D + t] = s;
  if (threadIdx.x < 4) {
    const int tt = (blk & 63)*4 + threadIdx.x;
    m0[b*D + tt] = q[b*D + tt];
  }
}

// ---------- per-hop ----------

// vm[b][t] = A[t,:].m ; hb[b][t] = b1[t] + q.w1[t][2D:3D] + m.w1[t][D:2D]
__global__ void k_pm2(const float* __restrict__ A, const float* __restrict__ w1,
                      const float* __restrict__ b1, const float* __restrict__ q,
                      const float* __restrict__ min_,
                      float* __restrict__ vm, float* __restrict__ hb) {
  const int blk = blockIdx.x;              // B*64
  const int b = blk >> 6;
  const int lane = threadIdx.x & 63, wave = threadIdx.x >> 6;
  const int t = (blk & 63)*4 + wave;
  const int l4 = lane * 4;
  float4 m4 = *(const float4*)(min_ + b*D + l4);
  float4 q4 = *(const float4*)(q + b*D + l4);
  float4 a4 = *(const float4*)(A + (size_t)t*D + l4);
  const float* w1r = w1 + (size_t)t*FEAT;
  float2 wm0 = *(const float2*)(w1r + D + l4);
  float2 wm1 = *(const float2*)(w1r + D + l4 + 2);
  float2 wq0 = *(const float2*)(w1r + 2*D + l4);
  float2 wq1 = *(const float2*)(w1r + 2*D + l4 + 2);
  float sv = a4.x*m4.x + a4.y*m4.y + a4.z*m4.z + a4.w*m4.w;
  float sh = m4.x*wm0.x + m4.y*wm0.y + m4.z*wm1.x + m4.w*wm1.y
           + q4.x*wq0.x + q4.y*wq0.y + q4.z*wq1.x + q4.w*wq1.y;
  sv = waveReduceSum(sv);
  sh = waveReduceSum(sh);
  if (lane == 0) { vm[b*D + t] = sv; hb[b*H + t] = b1[t] + sh; }
}

// WCB[b][h][k] = Wc + q*Wcq + m*Wcm + vq[k]*wdq[h] + vm[k]*wdm[h]  (bf16)
__global__ void k_comb(const float* __restrict__ w1, const float* __restrict__ q,
                       const float* __restrict__ min_,
                       const float* __restrict__ vq, const float* __restrict__ vm,
                       bf16_t* __restrict__ WCB) {
  int idx = blockIdx.x * 256 + threadIdx.x;  // B*DH
  int b = idx >> 16;
  int h = (idx >> 8) & 255;
  int k = idx & 255;
  const float* w1h = w1 + (size_t)h * FEAT;
  float v = w1h[k] + q[b*D + k]*w1h[3*D + k] + min_[b*D + k]*w1h[4*D + k]
          + vq[b*D + k]*w1h[7*D] + vm[b*D + k]*w1h[7*D + 1];
  WCB[idx] = (bf16_t)v;
}

// MFMA score v5: reg-staged c chunk -> compute aq/am once per block ->
// ds_write 3 swizzled LDS streams. 64 rows x 256 cols, 8 waves.
// LDS: dbuf d: base d*24576; stream s: +s*8192; row r: +r*128;
// physical slot p = logical ^ (r&7).
__global__ __launch_bounds__(512, 4) void k_score5(
    const bf16_t* __restrict__ CBF,
    const bf16_t* __restrict__ WCB, const bf16_t* __restrict__ WAQ,
    const bf16_t* __restrict__ WAM,
    const float* __restrict__ q, const float* __restrict__ min_,
    const float* __restrict__ hb, const float* __restrict__ w2,
    const float* __restrict__ b2, float* __restrict__ scores) {
  __shared__ char smem[49152];
  __shared__ float qshf[256], mshf[256];
  __shared__ float red[8][64];
  const int t = threadIdx.x;
  const int lane = t & 63, wave = t >> 6;
  const int r0 = blockIdx.x * 64;
  const int b = r0 >> 12;
  const int lrow = lane & 15;
  const int lk = (lane >> 4) * 8;
  const int n0 = wave * 32;

  if (t < 256) { qshf[t] = q[b*D + t]; mshf[t] = min_[b*D + t]; }

  // staging geometry: thread t -> row srow = t>>3, logical slot sl = t&7
  const int srow = t >> 3, sl = t & 7;
  const int sp = sl ^ (srow & 7);
  const int swbase = srow*128 + sp*16;
  const bf16_t* cgp = CBF + (size_t)(r0 + srow)*D + sl*8;

  const bf16_t* bptrC = WCB + (size_t)b*DH;
  const bf16_t* bptrQ = WAQ;
  const bf16_t* bptrM = WAM;

  f32x4 acc[4][2];
  #pragma unroll
  for (int mi = 0; mi < 4; mi++)
    #pragma unroll
    for (int ni = 0; ni < 2; ni++) acc[mi][ni] = (f32x4){0.f,0.f,0.f,0.f};

  bf16x8 breg[2][6];
  #define LOADB(ks) { \
    const int kelem = (ks)*32 + lk; \
    _Pragma("unroll") \
    for (int ni = 0; ni < 2; ni++) { \
      const size_t co = (size_t)(n0 + ni*16 + lrow) * D + kelem; \
      breg[(ks)&1][ni*3+0] = *(const bf16x8*)(bptrC + co); \
      breg[(ks)&1][ni*3+1] = *(const bf16x8*)(bptrQ + co); \
      breg[(ks)&1][ni*3+2] = *(const bf16x8*)(bptrM + co); \
    } }

  // compute aq/am from reg-staged c and write 3 LDS streams (chunk ch -> dbuf d)
  #define STAGEC(ch, d, cr) { \
    float qv_[8], mv_[8]; \
    *(float4*)(qv_)   = *(const float4*)(qshf + (ch)*64 + sl*8); \
    *(float4*)(qv_+4) = *(const float4*)(qshf + (ch)*64 + sl*8 + 4); \
    *(float4*)(mv_)   = *(const float4*)(mshf + (ch)*64 + sl*8); \
    *(float4*)(mv_+4) = *(const float4*)(mshf + (ch)*64 + sl*8 + 4); \
    bf16x8 aqv_, amv_; \
    _Pragma("unroll") \
    for (int i = 0; i < 8; i++) { \
      float cf_ = (float)(cr)[i]; \
      aqv_[i] = (bf16_t)fabsf(cf_ - qv_[i]); \
      amv_[i] = (bf16_t)fabsf(cf_ - mv_[i]); \
    } \
    char* lb_ = smem + (d)*24576 + swbase; \
    *(bf16x8*)(lb_)         = (cr); \
    *(bf16x8*)(lb_ + 8192)  = aqv_; \
    *(bf16x8*)(lb_ + 16384) = amv_; \
  }

  bf16x8 creg = *(const bf16x8*)(cgp);       // chunk 0
  LOADB(0);
  __syncthreads();                            // qshf/mshf visible
  STAGEC(0, 0, creg);
  __syncthreads();                            // staged chunk 0 visible

  #pragma unroll
  for (int ch = 0; ch < 4; ch++) {
    bf16x8 cnext;
    if (ch < 3) cnext = *(const bf16x8*)(cgp + (ch + 1)*64);   // early issue
    #pragma unroll
    for (int kk = 0; kk < 2; kk++) {
      const int ks = ch*2 + kk;
      if (ks < 7) LOADB(ks + 1);
      const int p = ((kk << 2) + (lane >> 4)) ^ (lane & 7);
      const char* lb = smem + (ch & 1)*24576;
      #pragma unroll
      for (int mi = 0; mi < 4; mi++) {
        const int ro = (mi*16 + lrow)*128 + p*16;
        bf16x8 ac = *(const bf16x8*)(lb + ro);
        bf16x8 aq = *(const bf16x8*)(lb + 8192 + ro);
        bf16x8 am = *(const bf16x8*)(lb + 16384 + ro);
        #pragma unroll
        for (int ni = 0; ni < 2; ni++) {
          acc[mi][ni] = __builtin_amdgcn_mfma_f32_16x16x32_bf16(ac, breg[ks&1][ni*3+0], acc[mi][ni], 0, 0, 0);
          acc[mi][ni] = __builtin_amdgcn_mfma_f32_16x16x32_bf16(aq, breg[ks&1][ni*3+1], acc[mi][ni], 0, 0, 0);
          acc[mi][ni] = __builtin_amdgcn_mfma_f32_16x16x32_bf16(am, breg[ks&1][ni*3+2], acc[mi][ni], 0, 0, 0);
        }
      }
    }
    if (ch < 3) STAGEC(ch + 1, (ch + 1) & 1, cnext);
    __syncthreads();
  }

  // epilogue: tanh + w2-dot, reduce over h (layout verified rounds 4-8)
  float hbv[2], w2v[2];
  #pragma unroll
  for (int ni = 0; ni < 2; ni++) {
    const int col = n0 + ni*16 + lrow;
    hbv[ni] = hb[b*H + col];
    w2v[ni] = w2[col];
  }
  #pragma unroll
  for (int mi = 0; mi < 4; mi++) {
    #pragma unroll
    for (int j = 0; j < 4; j++) {
      float ps = 0.f;
      #pragma unroll
      for (int ni = 0; ni < 2; ni++) {
        float x = acc[mi][ni][j] + hbv[ni];
        float ex = __expf(2.f * x);
        float th = 1.f - 2.f * __builtin_amdgcn_rcpf(ex + 1.f);
        ps += th * w2v[ni];
      }
      ps += __shfl_xor(ps, 1, 64);
      ps += __shfl_xor(ps, 2, 64);
      ps += __shfl_xor(ps, 4, 64);
      ps += __shfl_xor(ps, 8, 64);
      if (lrow == 0) red[wave][mi*16 + (lane >> 4)*4 + j] = ps;
    }
  }
  __syncthreads();
  if (t < 64) {
    float s = red[0][t] + red[1][t] + red[2][t] + red[3][t]
            + red[4][t] + red[5][t] + red[6][t] + red[7][t] + b2[0];
    scores[r0 + t] = s;
  }
}

// Masked softmax over S per batch.
__global__ __launch_bounds__(1024) void k_soft(const float* __restrict__ scores,
                                               const int* __restrict__ len_c,
                                               float* __restrict__ att) {
  const int b = blockIdx.x, t = threadIdx.x;
  const int len = len_c[b];
  __shared__ float rbuf[16];
  const float* sc = scores + b*S;
  float mx = -1e30f;
  for (int s = t; s < len; s += 1024) mx = fmaxf(mx, sc[s]);
  #pragma unroll
  for (int off = 32; off; off >>= 1) mx = fmaxf(mx, __shfl_xor(mx, off, 64));
  if ((t & 63) == 0) rbuf[t >> 6] = mx;
  __syncthreads();
  mx = rbuf[0];
  #pragma unroll
  for (int i = 1; i < 16; i++) mx = fmaxf(mx, rbuf[i]);
  __syncthreads();
  float sum = 0.f;
  float* ab = att + b*S;
  for (int s = t; s < S; s += 1024) {
    if (s < len) { float e = __expf(sc[s] - mx); ab[s] = e; sum += e; }
    else ab[s] = 0.f;
  }
  sum = waveReduceSum(sum);
  if ((t & 63) == 0) rbuf[t >> 6] = sum;
  __syncthreads();
  sum = 0.f;
  #pragma unroll
  for (int i = 0; i < 16; i++) sum += rbuf[i];
  const float inv = 1.f / sum;
  for (int s = t; s < len; s += 1024) ab[s] *= inv;
}

// epart from bf16 c — lanes read consecutive 2B: coalesced.
__global__ void k_epart_bf(const bf16_t* __restrict__ CBF, const float* __restrict__ att,
                           const int* __restrict__ len_c, float* __restrict__ epart) {
  const int b = blockIdx.x >> 6, ch = blockIdx.x & 63;
  const int t = threadIdx.x;
  const int len = len_c[b];
  const int s0 = ch * (S / NCH);
  const int send = min(s0 + (S / NCH), len);
  float acc = 0.f;
  const float* ab = att + b*S;
  int s = s0;
  for (; s + 3 < send; s += 4) {
    float a0 = ab[s], a1 = ab[s+1], a2 = ab[s+2], a3 = ab[s+3];
    const bf16_t* cp = CBF + (size_t)(b*S + s)*D + t;
    acc += a0*(float)cp[0] + a1*(float)cp[D] + a2*(float)cp[2*D] + a3*(float)cp[3*D];
  }
  for (; s < send; s++) acc += ab[s] * (float)CBF[(size_t)(b*S + s)*D + t];
  epart[(ch*B + b)*D + t] = acc;
}

// GRU: es = sum(epart); 6 coalesced wave-dots per t; gates elementwise.
__global__ __launch_bounds__(256) void k_gru2(
    const float* __restrict__ wih, const float* __restrict__ whh,
    const float* __restrict__ bih, const float* __restrict__ bhh,
    const float* __restrict__ epart, const float* __restrict__ min_,
    float* __restrict__ mout, float* __restrict__ out, const int write_out) {
  const int blk = blockIdx.x;         // B*16
  const int b = blk >> 4;
  const int t0 = (blk & 15) << 4;
  const int t = threadIdx.x;
  const int lane = t & 63, wave = t >> 6;
  __shared__ float es[D], ms[D];
  float e = 0.f;
  #pragma unroll
  for (int ch = 0; ch < NCH; ch++) e += epart[(ch*B + b)*D + t];
  es[t] = e;
  ms[t] = min_[b*D + t];
  __syncthreads();
  const int l4 = lane * 4;
  float4 e4 = *(const float4*)(es + l4);
  float4 m4 = *(const float4*)(ms + l4);
  #pragma unroll
  for (int tl = 0; tl < 4; tl++) {
    const int tt = t0 + wave*4 + tl;
    float g[6];
    #pragma unroll
    for (int gg = 0; gg < 3; gg++) {
      const int j = gg*D + tt;
      const float4 wi4 = *(const float4*)(wih + (size_t)j*D + l4);
      const float4 wh4 = *(const float4*)(whh + (size_t)j*D + l4);
      float gi = e4.x*wi4.x + e4.y*wi4.y + e4.z*wi4.z + e4.w*wi4.w;
      float gh = m4.x*wh4.x + m4.y*wh4.y + m4.z*wh4.z + m4.w*wh4.w;
      g[gg]   = waveReduceSum(gi);
      g[3+gg] = waveReduceSum(gh);
    }
    if (lane == 0) {
      const int j0 = tt, j1 = D + tt, j2 = 2*D + tt;
      float gir = g[0] + bih[j0], giz = g[1] + bih[j1], gin = g[2] + bih[j2];
      float ghr = g[3] + bhh[j0], ghz = g[4] + bhh[j1], ghn = g[5] + bhh[j2];
      float rr = 1.f / (1.f + __expf(-(gir + ghr)));
      float zz = 1.f / (1.f + __expf(-(giz + ghz)));
      float nn = tanhf(gin + rr * ghn);
      float mn = (1.f - zz)*nn + zz*ms[tt];
      mout[b*D + tt] = mn;
      if (write_out) out[b*D + tt] = mn;
    }
  }
}

extern "C" void kernel_launch(void* const* d_in, const int* in_sizes, int n_in,
                              void* d_out, int out_size, void* d_ws, size_t ws_size,
                              hipStream_t stream) {
  const float* c   = (const float*)d_in[0];
  const float* q   = (const float*)d_in[1];
  const int*   len = (const int*)d_in[2];
  const float* A   = (const float*)d_in[3];
  const float* w1  = (const float*)d_in[4];
  const float* b1  = (const float*)d_in[5];
  const float* w2  = (const float*)d_in[6];
  const float* b2  = (const float*)d_in[7];
  const float* wih = (const float*)d_in[8];
  const float* whh = (const float*)d_in[9];
  const float* bih = (const float*)d_in[10];
  const float* bhh = (const float*)d_in[11];
  float* out = (float*)d_out;

  bf16_t* WCB = (bf16_t*)d_ws;
  bf16_t* WAQ = WCB + (size_t)B*DH;
  bf16_t* WAM = WAQ + DH;
  bf16_t* CBF = WAM + DH;
  float* fb = (float*)(CBF + (size_t)R*D);
  float* vq    = fb;
  float* vm    = vq + B*D;
  float* hb    = vm + B*D;
  float* m0    = hb + B*H;
  float* m1    = m0 + B*D;
  float* epart = m1 + B*D;
  float* sc    = epart + (size_t)NCH*B*D;

  k_prec<<<R*D/2048 + DH/256, 256, 0, stream>>>(c, w1, CBF, WAQ, WAM);
  k_p02<<<B*64, 256, 0, stream>>>(q, A, vq, m0);

  for (int it = 0; it < 3; ++it) {
    float* min_ = (it & 1) ? m1 : m0;
    float* mout = (it & 1) ? m0 : m1;
    k_pm2<<<B*64, 256, 0, stream>>>(A, w1, b1, q, min_, vm, hb);
    k_comb<<<B*DH/256, 256, 0, stream>>>(w1, q, min_, vq, vm, WCB);
    k_score5<<<R/64, 512, 0, stream>>>(CBF, WCB, WAQ, WAM, q, min_, hb, w2, b2, sc);
    float* att = out + B*D + (size_t)it*R;
    k_soft<<<B, 1024, 0, stream>>>(sc, len, att);
    k_epart_bf<<<B*NCH, 256, 0, stream>>>(CBF, att, len, epart);
    k_gru2<<<B*16, 256, 0, stream>>>(wih, whh, bih, bhh, epart, min_, mout, out, it == 2 ? 1 : 0);
  }
}